// Round 5
// baseline (13095.236 us; speedup 1.0000x reference)
//
#include <hip/hip_runtime.h>
#include <cstdint>
#include <cstddef>

#define T_ 2048
#define N_ 64
#define L_ 300
#define V_ 35
#define E_ 256
#define H_ 512
#define KS_ 128

typedef __attribute__((ext_vector_type(8))) short short8;
typedef __attribute__((ext_vector_type(4))) float float4v;

struct Params {
    // inputs (setup_inputs order)
    const float *key, *values;
    const int *x_lens, *text;
    const float *emb_W;
    const float *W_ih1, *W_hh1, *b_ih1, *b_hh1;
    const float *W_ih2, *W_hh2, *b_ih2, *b_hh2;
    const float *W_ih3, *W_hh3, *b_ih3, *b_hh3;
    const float *b_out;
    // workspace
    unsigned short *W1P, *W2P, *W3P;   // MFMA-fragment-packed bf16 weights
    float *embproj;                    // [V][2048] = emb_W@W_ih1[:,:256]^T + b_ih1 + b_hh1
    float *b2, *b3;
    unsigned short *keyP;              // packed A-frag layout [n][t16][kq][lane][8]
    unsigned short *valP;              // row-major [n][t][128] bf16
    unsigned int *bar;                 // [4 domains][64] flag array
    unsigned int *h1x0, *h1x1, *h2x0, *h2x1;  // [64][256] uint (bf16 pairs)
    float *h3xF;                       // [64][128] f32 h3 exchange
    float *mqb, *sqb;                  // [64*4] per-quarter max / sum
    float *ctxqb;                      // [64][4][128] per-quarter ctx partials
    float *out;
};

__device__ __forceinline__ float b2f(unsigned short u) {
    unsigned int i = ((unsigned int)u) << 16;
    float f; __builtin_memcpy(&f, &i, 4); return f;
}
__device__ __forceinline__ unsigned short f2b(float f) {
    unsigned int i; __builtin_memcpy(&i, &f, 4);
    i += 0x7FFFu + ((i >> 16) & 1u);
    return (unsigned short)(i >> 16);
}
__device__ __forceinline__ unsigned int packf2(float a, float b) {
    return (unsigned int)f2b(a) | ((unsigned int)f2b(b) << 16);
}
__device__ __forceinline__ float sigm(float x) { return 1.0f / (1.0f + __expf(-x)); }
__device__ __forceinline__ float tanh_(float x) {
    float e = __expf(2.0f * x);
    return 1.0f - 2.0f / (e + 1.0f);
}
__device__ __forceinline__ float wredsum(float v) {
#pragma unroll
    for (int o = 32; o > 0; o >>= 1) v += __shfl_down(v, o);
    return v;
}

// agent-scope coherent exchange primitives
__device__ __forceinline__ unsigned int cohLd(const unsigned int* p) {
    return __hip_atomic_load(p, __ATOMIC_RELAXED, __HIP_MEMORY_SCOPE_AGENT);
}
__device__ __forceinline__ void cohSt(unsigned int* p, unsigned int v) {
    __hip_atomic_store(p, v, __ATOMIC_RELAXED, __HIP_MEMORY_SCOPE_AGENT);
}
__device__ __forceinline__ float cohLdF(const float* p) {
    unsigned int u = __hip_atomic_load((const unsigned int*)p, __ATOMIC_RELAXED, __HIP_MEMORY_SCOPE_AGENT);
    float f; __builtin_memcpy(&f, &u, 4); return f;
}
__device__ __forceinline__ void cohStF(float* p, float v) {
    unsigned int u; __builtin_memcpy(&u, &v, 4);
    __hip_atomic_store((unsigned int*)p, u, __ATOMIC_RELAXED, __HIP_MEMORY_SCOPE_AGENT);
}

// Split flag-array barrier over a 64-WG domain.
// arrive: drain own publishes (vmcnt only) + set own flag.
// wait:   one wave vector-polls all 64 flags. Monotone epochs, no reset.
// Loads of STABLE data issued between arrive and wait overlap the poll.
__device__ __forceinline__ void gbar_arrive(unsigned int* flags, int slot,
                                            unsigned int ep, int tid)
{
    asm volatile("s_waitcnt vmcnt(0)" ::: "memory");
    __syncthreads();
    if (tid == 0)
        __hip_atomic_store(flags + slot, ep, __ATOMIC_RELAXED, __HIP_MEMORY_SCOPE_AGENT);
}
__device__ __forceinline__ void gbar_wait(unsigned int* flags, unsigned int ep, int tid)
{
    if (tid < 64) {
        while (__hip_atomic_load(flags + tid, __ATOMIC_RELAXED, __HIP_MEMORY_SCOPE_AGENT) < ep)
            __builtin_amdgcn_s_sleep(1);
    }
    __syncthreads();
}

struct __align__(16) ShAB {
    unsigned short xs[16][1032];     // staged A rows (K<=1024, +8 pad)
    float gld[2][4][16][16];         // [ntile][ksplit][col][m] partials
};
struct __align__(16) ShC {
    unsigned int xk3u[320];          // [h2(512)||h3prev(128)] bf16 pairs
    float g3L[4][32];                // gates for this WG's 32-hu slice
};
struct __align__(16) ShD {
    float attl[512];
    float ctxp[32][129];
    float red[128];
    float lsum[V_][8];
};
union __align__(16) ShU { ShAB ab; ShC c; ShD d; };

// Batched 16(m) x 32(cols) GEMM step; 8 waves = 2 ntiles x 4 k-splits.
template <int NKT>
__device__ __forceinline__ void gemm_ab(const unsigned short* xs,
                                        const unsigned short* wb,
                                        float (*gld)[4][16][16], int tid)
{
    const int lane = tid & 63, wv = tid >> 6;
    const int nt = wv & 1, ks = wv >> 1;
    constexpr int KTW = NKT / 4;
    float4v acc = {0.f, 0.f, 0.f, 0.f};
    const unsigned short* ar = xs + (lane & 15) * 1032 + ks * KTW * 32 + (lane >> 4) * 8;
    const unsigned short* wp = wb + ((size_t)(nt * NKT + ks * KTW)) * 512 + lane * 8;
#pragma unroll
    for (int k = 0; k < KTW; k++)
        acc = __builtin_amdgcn_mfma_f32_16x16x32_bf16(
            *(const short8*)(ar + k * 32), *(const short8*)(wp + (size_t)k * 512), acc, 0, 0, 0);
    const int q8 = lane >> 4, l15 = lane & 15;
#pragma unroll
    for (int r = 0; r < 4; r++) gld[nt][ks][l15][q8 * 4 + r] = acc[r];
}

__global__ __launch_bounds__(512) void decoder_main(Params p)
{
    __shared__ float c1L[128], c2L[128], c3L[32], h3sL[128];
    __shared__ float ctxf16[16][128];
    __shared__ float fL[16][4];
    __shared__ unsigned short h3bL[128];
    __shared__ ShU su;
    const int tid = threadIdx.x, wg = blockIdx.x;   // 256 WGs x 512
    const int lane = tid & 63, wv = tid >> 6;
    const int mt = wg & 3, cp = wg >> 2;            // GEMM role
    const int ownr = (wg >> 2) & 15, q = wg >> 6;   // attention role: n within own m-tile
    const int n = mt * 16 + ownr;
    const int len = p.x_lens[n];
    const int rows_q = min(max(len - q * 512, 0), 512);
    float* const attnout = p.out + (size_t)N_ * L_ * V_ + (size_t)n * L_ * T_ + q * 512;
    unsigned int* const flags = p.bar + mt * 64;    // mt-local barrier domain
    unsigned int ep = 0;

    if (tid < 128) { c1L[tid] = 0.f; c2L[tid] = 0.f; h3sL[tid] = 0.f; }
    if (tid < 32) c3L[tid] = 0.f;
    __syncthreads();

    const unsigned short* W1b = p.W1P + (size_t)cp * (2 * 20 * 512);
    const unsigned short* W2b = p.W2P + (size_t)cp * (2 * 32 * 512);
    const unsigned short* W3b = p.W3P + (size_t)(q * 8) * (20 * 512);

    unsigned int prefH1[10];      // phase-A staging prefetch (h1prev part)
#pragma unroll
    for (int i = 0; i < 10; i++) prefH1[i] = 0u;   // h1_0 = 0

    // flash-combine for step lp: att write (own quarter), ctx for own 16 rows, logits (q0)
    auto combine = [&](int lp) {
        // issue ctxqb loads FIRST (independent of fL) so they overlap the m/s reduction
        const int nr = tid >> 5, e0i = (tid & 31) * 4;
        float cq[4][4];
#pragma unroll
        for (int qq = 0; qq < 4; qq++) {
            const float* b = p.ctxqb + ((size_t)(mt * 16 + nr) * 4 + qq) * 128 + e0i;
#pragma unroll
            for (int j = 0; j < 4; j++) cq[qq][j] = cohLdF(b + j);
        }
        if (tid < 64)       su.d.red[tid] = cohLdF(p.mqb + mt * 64 + tid);
        else if (tid < 128) su.d.red[tid] = cohLdF(p.sqb + mt * 64 + (tid - 64));
        __syncthreads();
        if (tid < 16) {
            float m0 = su.d.red[tid * 4], m1 = su.d.red[tid * 4 + 1],
                  m2 = su.d.red[tid * 4 + 2], m3 = su.d.red[tid * 4 + 3];
            float M = fmaxf(fmaxf(m0, m1), fmaxf(m2, m3));
            float e0 = __expf(m0 - M), e1 = __expf(m1 - M),
                  e2 = __expf(m2 - M), e3 = __expf(m3 - M);
            float S = su.d.red[64 + tid * 4] * e0 + su.d.red[64 + tid * 4 + 1] * e1
                    + su.d.red[64 + tid * 4 + 2] * e2 + su.d.red[64 + tid * 4 + 3] * e3;
            float rS = 1.0f / S;
            fL[tid][0] = e0 * rS; fL[tid][1] = e1 * rS;
            fL[tid][2] = e2 * rS; fL[tid][3] = e3 * rS;
        }
        __syncthreads();
        {
            float fq = fL[ownr][q];
            if (tid < rows_q)
                __builtin_nontemporal_store(su.d.attl[tid] * fq,
                                            attnout + (size_t)lp * T_ + tid);
        }
        {
            float s0 = 0.f, s1 = 0.f, s2 = 0.f, s3 = 0.f;
#pragma unroll
            for (int qq = 0; qq < 4; qq++) {
                float f = fL[nr][qq];
                s0 += cq[qq][0] * f; s1 += cq[qq][1] * f;
                s2 += cq[qq][2] * f; s3 += cq[qq][3] * f;
            }
            ctxf16[nr][e0i] = s0; ctxf16[nr][e0i + 1] = s1;
            ctxf16[nr][e0i + 2] = s2; ctxf16[nr][e0i + 3] = s3;
        }
        __syncthreads();
        if (q == 0) {   // logits for own n (q is WG-uniform; barriers below are safe)
            if (tid < V_ * 8) {
                const int v = tid >> 3, oc = tid & 7;
                const float* er = p.emb_W + (size_t)v * E_ + oc * 32;
                const float* src = (oc < 4) ? (h3sL + oc * 32) : (&ctxf16[ownr][0] + oc * 32 - 128);
                float s = 0.f;
#pragma unroll
                for (int j2 = 0; j2 < 32; j2++) s += src[j2] * er[j2];
                su.d.lsum[v][oc] = s;
            }
            __syncthreads();
            if (tid < V_) {
                float s = p.b_out[tid];
#pragma unroll
                for (int j2 = 0; j2 < 8; j2++) s += su.d.lsum[tid][j2];
                p.out[((size_t)n * L_ + lp) * V_ + tid] = s;
            }
        }
    };

    for (int l = 0; l < L_; ++l) {
        const unsigned int* h2prev = (l & 1) ? p.h2x1 : p.h2x0;
        unsigned int* h1cur        = (l & 1) ? p.h1x0 : p.h1x1;
        unsigned int* h2cur        = (l & 1) ? p.h2x0 : p.h2x1;

        // ===== Phase A: combine(l-1) + LSTM1 (K = [ctx||h1prev], emb in embproj) =====
        gbar_wait(flags, ep, tid);          // D1(l-1) done (trivial at l==0)
        // early-issue embproj rows (stable inputs; hidden under combine+staging+gemm)
        float ebv[4];
        if (tid < 128) {
            const int m2e = mt * 16 + (tid & 15);
            const float* eb = p.embproj + (size_t)p.text[m2e * L_ + l] * 2048
                            + cp * 8 + (tid >> 4);
#pragma unroll
            for (int g = 0; g < 4; g++) ebv[g] = eb[g * 512];
        }
        if (l > 0) {
            combine(l - 1);
        } else {
            float* cf = &ctxf16[0][0];
            cf[tid * 4] = 0.f; cf[tid * 4 + 1] = 0.f;
            cf[tid * 4 + 2] = 0.f; cf[tid * 4 + 3] = 0.f;
        }
        __syncthreads();
        {
            unsigned int* xsu = (unsigned int*)&su.ab.xs[0][0];
#pragma unroll
            for (int i = 0; i < 10; i++) {
                int idx = tid + i * 512;
                int r = idx / 320, c = idx - r * 320;
                unsigned int u = (c < 64)
                    ? packf2(ctxf16[r][2 * c], ctxf16[r][2 * c + 1])
                    : prefH1[i];
                xsu[r * 516 + c] = u;
            }
        }
        __syncthreads();
        gemm_ab<20>(&su.ab.xs[0][0], W1b, su.ab.gld, tid);
        __syncthreads();
        if (tid < 128) {
            const int mm = tid & 15, j = tid >> 4;
            const int m2 = mt * 16 + mm;
            float gv[4];
#pragma unroll
            for (int g = 0; g < 4; g++) {
                int ntq = g >> 1, lq = (g & 1) * 8 + j;
                float s = 0.f;
#pragma unroll
                for (int k2 = 0; k2 < 4; k2++) s += su.ab.gld[ntq][k2][lq][mm];
                gv[g] = s + ebv[g];
            }
            float c = sigm(gv[1]) * c1L[tid] + sigm(gv[0]) * tanh_(gv[2]);
            c1L[tid] = c;
            unsigned int hb = (unsigned int)f2b(sigm(gv[3]) * tanh_(c));
            unsigned int ob = (unsigned int)__shfl_xor((int)hb, 16);
            if (!(j & 1)) cohSt(h1cur + m2 * 256 + cp * 4 + (j >> 1), hb | (ob << 16));
        }
        ++ep; gbar_arrive(flags, cp, ep, tid);

        // prefetch h2prev (stable since last step's B) while barrier propagates
        unsigned int prefH2[16];
        if (tid >= 256) {
#pragma unroll
            for (int i = 0; i < 16; i++)
                prefH2[i] = cohLd(h2prev + (mt * 16 + i) * 256 + (tid - 256));
        }
        gbar_wait(flags, ep, tid);

        // ===== Phase B: LSTM2, K = [h1(512)||h2prev(512)] =====
        {
            unsigned int* xsu = (unsigned int*)&su.ab.xs[0][0];
#pragma unroll
            for (int i = 0; i < 16; i++) {
                unsigned int u = (tid < 256) ? cohLd(h1cur + (mt * 16 + i) * 256 + tid)
                                             : prefH2[i];
                xsu[i * 516 + tid] = u;
            }
            __syncthreads();
            gemm_ab<32>(&su.ab.xs[0][0], W2b, su.ab.gld, tid);
            __syncthreads();
            if (tid < 128) {
                const int mm = tid & 15, j = tid >> 4;
                const int m2 = mt * 16 + mm;
                float gv[4];
#pragma unroll
                for (int g = 0; g < 4; g++) {
                    int ntq = g >> 1, lq = (g & 1) * 8 + j;
                    float s = 0.f;
#pragma unroll
                    for (int k2 = 0; k2 < 4; k2++) s += su.ab.gld[ntq][k2][lq][mm];
                    gv[g] = s + p.b2[g * 512 + cp * 8 + j];
                }
                float c = sigm(gv[1]) * c2L[tid] + sigm(gv[0]) * tanh_(gv[2]);
                c2L[tid] = c;
                unsigned int hb = (unsigned int)f2b(sigm(gv[3]) * tanh_(c));
                unsigned int ob = (unsigned int)__shfl_xor((int)hb, 16);
                if (!(j & 1)) cohSt(h2cur + m2 * 256 + cp * 4 + (j >> 1), hb | (ob << 16));
            }
        }
        ++ep; gbar_arrive(flags, cp, ep, tid);
        gbar_wait(flags, ep, tid);

        // ===== Phase C: LSTM3 gates (col-sliced MFMA) + h3 exchange =====
        {
            if (tid < 256) su.c.xk3u[tid] = cohLd(h2cur + n * 256 + tid);
            if (tid >= 256 && tid < 320) {
                int i2 = tid - 256;
                su.c.xk3u[256 + i2] = packf2(h3sL[2 * i2], h3sL[2 * i2 + 1]);
            }
            __syncthreads();
            const unsigned short* xb = (const unsigned short*)su.c.xk3u;
            const int q8 = lane >> 4;
            float4v acc = {0.f, 0.f, 0.f, 0.f};
            const unsigned short* ap = W3b + (size_t)wv * (20 * 512) + lane * 8;
#pragma unroll
            for (int kt = 0; kt < 20; kt++)
                acc = __builtin_amdgcn_mfma_f32_16x16x32_bf16(
                    *(const short8*)(ap + (size_t)kt * 512),
                    *(const short8*)(xb + kt * 32 + q8 * 8), acc, 0, 0, 0);
            if ((lane & 15) == 0) {
                const int g = wv >> 1, hl = (wv & 1) * 16 + q8 * 4;
                const float4v bb = *(const float4v*)(p.b3 + g * 128 + q * 32 + hl);
#pragma unroll
                for (int r = 0; r < 4; r++) su.c.g3L[g][hl + r] = acc[r] + bb[r];
            }
            __syncthreads();
            if (tid < 32) {
                float gi = sigm(su.c.g3L[0][tid]);
                float gf = sigm(su.c.g3L[1][tid]);
                float gg = tanh_(su.c.g3L[2][tid]);
                float go = sigm(su.c.g3L[3][tid]);
                float c = gf * c3L[tid] + gi * gg;
                c3L[tid] = c;
                cohStF(p.h3xF + n * 128 + q * 32 + tid, go * tanh_(c));
            }
        }
        ++ep; gbar_arrive(flags, cp, ep, tid);

        // prefetch ALL key fragments (input-constant) while barrier propagates
        short8 kf[4][4];
        {
            const unsigned short* kpb = p.keyP + ((size_t)n * 128 + q * 32) * 2048;
#pragma unroll
            for (int i = 0; i < 4; i++) {
                int tl = wv * 4 + i;
                if (tl * 16 < rows_q) {
                    const unsigned short* ab2 = kpb + (size_t)tl * 2048 + lane * 8;
                    kf[i][0] = *(const short8*)(ab2);
                    kf[i][1] = *(const short8*)(ab2 + 512);
                    kf[i][2] = *(const short8*)(ab2 + 1024);
                    kf[i][3] = *(const short8*)(ab2 + 1536);
                }
            }
        }
        gbar_wait(flags, ep, tid);

        // ===== Phase D1: energies (MFMA, prefetched key) + local softmax + ctx partial =====
        {
            if (tid < 128) {
                float h = cohLdF(p.h3xF + n * 128 + tid);
                h3sL[tid] = h;
                h3bL[tid] = f2b(h);
            }
            __syncthreads();
            const int q8 = lane >> 4, l15 = lane & 15;
            short8 bfr[4];
#pragma unroll
            for (int kq = 0; kq < 4; kq++)
                bfr[kq] = *(const short8*)(h3bL + kq * 32 + q8 * 8);
            float mloc = -1e30f;
#pragma unroll
            for (int i = 0; i < 4; i++) {
                int tl = wv * 4 + i;
                if (tl * 16 < rows_q) {
                    float4v acc = {0.f, 0.f, 0.f, 0.f};
                    acc = __builtin_amdgcn_mfma_f32_16x16x32_bf16(kf[i][0], bfr[0], acc, 0, 0, 0);
                    acc = __builtin_amdgcn_mfma_f32_16x16x32_bf16(kf[i][1], bfr[1], acc, 0, 0, 0);
                    acc = __builtin_amdgcn_mfma_f32_16x16x32_bf16(kf[i][2], bfr[2], acc, 0, 0, 0);
                    acc = __builtin_amdgcn_mfma_f32_16x16x32_bf16(kf[i][3], bfr[3], acc, 0, 0, 0);
                    int t0 = tl * 16 + q8 * 4;
#pragma unroll
                    for (int r = 0; r < 4; r++) {
                        float e = (t0 + r < rows_q) ? acc[r] : -1e30f;
                        acc[r] = e;
                        mloc = fmaxf(mloc, e);
                    }
                    if (l15 == 0) *(float4v*)(su.d.attl + t0) = acc;
                }
            }
            mloc = fmaxf(mloc, __shfl_xor(mloc, 16));
            mloc = fmaxf(mloc, __shfl_xor(mloc, 32));
            if (lane == 0) su.d.red[96 + wv] = mloc;
            __syncthreads();
            if (tid == 0) {
                float M2 = su.d.red[96];
                for (int i2 = 1; i2 < 8; i2++) M2 = fmaxf(M2, su.d.red[96 + i2]);
                su.d.red[112] = M2;
            }
            __syncthreads();
            const float M2 = su.d.red[112];
            float pv = (tid < rows_q) ? __expf(su.d.attl[tid] - M2) : 0.f;
            su.d.attl[tid] = pv;
            float ps = wredsum(pv);
            if (lane == 0) su.d.red[104 + wv] = ps;
            __syncthreads();
            if (tid == 0) {
                float s = 0.f;
                for (int i2 = 0; i2 < 8; i2++) s += su.d.red[104 + i2];
                cohStF(p.mqb + n * 4 + q, M2);
                cohStF(p.sqb + n * 4 + q, s);
            }
            __syncthreads();
            // ctx partial (unnormalized), 4-deep unrolled val stream
            {
                const int tg = tid >> 4, e8 = tid & 15;
                float a8[8] = {0, 0, 0, 0, 0, 0, 0, 0};
                const unsigned short* vb = p.valP + ((size_t)n * 2048 + q * 512) * 128 + e8 * 8;
                int t = tg;
                for (; t + 96 < rows_q; t += 128) {
                    short8 v0 = *(const short8*)(vb + (size_t)t * 128);
                    short8 v1 = *(const short8*)(vb + (size_t)(t + 32) * 128);
                    short8 v2 = *(const short8*)(vb + (size_t)(t + 64) * 128);
                    short8 v3 = *(const short8*)(vb + (size_t)(t + 96) * 128);
                    float w0 = su.d.attl[t], w1 = su.d.attl[t + 32];
                    float w2 = su.d.attl[t + 64], w3 = su.d.attl[t + 96];
#pragma unroll
                    for (int j = 0; j < 8; j++)
                        a8[j] += w0 * b2f((unsigned short)v0[j]) + w1 * b2f((unsigned short)v1[j])
                               + w2 * b2f((unsigned short)v2[j]) + w3 * b2f((unsigned short)v3[j]);
                }
                for (; t < rows_q; t += 32) {
                    float w = su.d.attl[t];
                    short8 v8 = *(const short8*)(vb + (size_t)t * 128);
#pragma unroll
                    for (int j = 0; j < 8; j++) a8[j] += w * b2f((unsigned short)v8[j]);
                }
#pragma unroll
                for (int j = 0; j < 8; j++) su.d.ctxp[tg][e8 * 8 + j] = a8[j];
            }
            __syncthreads();
            if (tid < 128) {
                float s = 0.f;
#pragma unroll 8
                for (int g2 = 0; g2 < 32; g2++) s += su.d.ctxp[g2][tid];
                cohStF(p.ctxqb + ((size_t)n * 4 + q) * 128 + tid, s);
            }
        }
        ++ep; gbar_arrive(flags, cp, ep, tid);

        // prefetch next step's h1prev (= h1cur published in this step's A; stable)
        if (l + 1 < L_) {
#pragma unroll
            for (int i = 0; i < 10; i++) {
                int idx = tid + i * 512;
                int r = idx / 320, c = idx - r * 320;
                if (c >= 64)
                    prefH1[i] = cohLd(h1cur + (mt * 16 + r) * 256 + (c - 64));
            }
        }
    }
    // final step's att + logits
    gbar_wait(flags, ep, tid);
    combine(L_ - 1);
}

// ---------------- setup kernels ----------------
__global__ void setup_weights(Params p)
{
    size_t stride = (size_t)gridDim.x * blockDim.x;
    size_t i0 = (size_t)blockIdx.x * blockDim.x + threadIdx.x;
    // W1P [cp][nt][kt20][lane][8]; K = [ctx(128)->W_ih1 cols 256.. || h1(512)->W_hh1]
    for (size_t i = i0; i < (size_t)1310720; i += stride) {
        int e = (int)(i & 7), ln = (int)((i >> 3) & 63), blk = (int)(i >> 9);
        int kt = blk % 20, nt = (blk / 20) & 1, cpp = blk / 40;
        int l15 = ln & 15, q8 = ln >> 4;
        int col = (2 * nt + (l15 >> 3)) * 512 + cpp * 8 + (l15 & 7);
        int k = kt * 32 + q8 * 8 + e;
        float v = (k < 128) ? p.W_ih1[(size_t)col * 384 + 256 + k]
                            : p.W_hh1[(size_t)col * 512 + (k - 128)];
        p.W1P[i] = f2b(v);
    }
    // W2P [cp][nt][kt32][lane][8]; K = [h1 || h2prev]
    for (size_t i = i0; i < (size_t)2097152; i += stride) {
        int e = (int)(i & 7), ln = (int)((i >> 3) & 63), blk = (int)(i >> 9);
        int kt = blk & 31, nt = (blk >> 5) & 1, cpp = blk >> 6;
        int l15 = ln & 15, q8 = ln >> 4;
        int col = (2 * nt + (l15 >> 3)) * 512 + cpp * 8 + (l15 & 7);
        int k = kt * 32 + q8 * 8 + e;
        float v = (k < 512) ? p.W_ih2[(size_t)col * 512 + k]
                            : p.W_hh2[(size_t)col * 512 + (k - 512)];
        p.W2P[i] = f2b(v);
    }
    // W3P [q][tile8][kt20][lane][8]; rows = gate cols; K = [h2(512) || h3prev(128)]
    for (size_t i = i0; i < (size_t)327680; i += stride) {
        int e = (int)(i & 7), ln = (int)((i >> 3) & 63), blk = (int)(i >> 9);
        int kt = blk % 20, tile = (blk / 20) & 7, qq = blk / 160;
        int l15 = ln & 15, q8 = ln >> 4;
        int col = (tile >> 1) * 128 + qq * 32 + (tile & 1) * 16 + l15;
        int k = kt * 32 + q8 * 8 + e;
        float v = (k < 512) ? p.W_ih3[(size_t)col * 512 + k]
                            : p.W_hh3[(size_t)col * 128 + (k - 512)];
        p.W3P[i] = f2b(v);
    }
    for (size_t i = i0; i < 2048; i += stride) p.b2[i] = p.b_ih2[i] + p.b_hh2[i];
    for (size_t i = i0; i < 512; i += stride) p.b3[i] = p.b_ih3[i] + p.b_hh3[i];
}

// embproj[c][j] = emb_W[c] . W_ih1[j][:256] + b_ih1[j] + b_hh1[j]
__global__ void setup_embproj(Params p)
{
    int idx = blockIdx.x * blockDim.x + threadIdx.x;
    if (idx >= V_ * 2048) return;
    int c = idx >> 11, j = idx & 2047;
    float s = p.b_ih1[j] + p.b_hh1[j];
    const float* er = p.emb_W + (size_t)c * E_;
    const float* wr = p.W_ih1 + (size_t)j * 384;
    for (int k = 0; k < 256; k++) s += er[k] * wr[k];
    p.embproj[idx] = s;
}

__global__ void setup_kv(Params p)
{
    size_t stride = (size_t)gridDim.x * blockDim.x;
    const size_t total = (size_t)T_ * N_ * KS_;
    for (size_t idx = (size_t)blockIdx.x * blockDim.x + threadIdx.x; idx < total; idx += stride) {
        int t = (int)(idx >> 13);
        int rem = (int)(idx & 8191);
        int n = rem >> 7, k = rem & 127;
        p.valP[((size_t)n * 2048 + t) * 128 + k] = f2b(p.values[idx]);
        size_t dst = (((size_t)n * 128 + (t >> 4)) * 4 + (k >> 5)) * 512
                   + ((((k >> 3) & 3) * 16 + (t & 15)) * 8) + (k & 7);
        p.keyP[dst] = f2b(p.key[idx]);
    }
}

// ---------------- host ----------------
extern "C" void kernel_launch(void* const* d_in, const int* in_sizes, int n_in,
                              void* d_out, int out_size, void* d_ws, size_t ws_size,
                              hipStream_t stream)
{
    (void)in_sizes; (void)n_in; (void)out_size; (void)ws_size;
    Params p;
    p.key    = (const float*)d_in[0];
    p.values = (const float*)d_in[1];
    p.x_lens = (const int*)d_in[2];
    p.text   = (const int*)d_in[3];
    p.emb_W  = (const float*)d_in[4];
    p.W_ih1  = (const float*)d_in[5];
    p.W_hh1  = (const float*)d_in[6];
    p.b_ih1  = (const float*)d_in[7];
    p.b_hh1  = (const float*)d_in[8];
    p.W_ih2  = (const float*)d_in[9];
    p.W_hh2  = (const float*)d_in[10];
    p.b_ih2  = (const float*)d_in[11];
    p.b_hh2  = (const float*)d_in[12];
    p.W_ih3  = (const float*)d_in[13];
    p.W_hh3  = (const float*)d_in[14];
    p.b_ih3  = (const float*)d_in[15];
    p.b_hh3  = (const float*)d_in[16];
    p.b_out  = (const float*)d_in[17];
    p.out    = (float*)d_out;

    char* w = (char*)d_ws;
    auto alloc = [&](size_t bytes) -> char* {
        char* r = w;
        w += (bytes + 255) & ~(size_t)255;
        return r;
    };
    p.W1P     = (unsigned short*)alloc((size_t)1310720 * 2);
    p.W2P     = (unsigned short*)alloc((size_t)2097152 * 2);
    p.W3P     = (unsigned short*)alloc((size_t)327680 * 2);
    p.embproj = (float*)alloc((size_t)V_ * 2048 * 4);
    p.b2      = (float*)alloc(2048 * 4);
    p.b3      = (float*)alloc(512 * 4);
    p.keyP    = (unsigned short*)alloc((size_t)16777216 * 2);
    p.valP    = (unsigned short*)alloc((size_t)16777216 * 2);
    char* zstart = w;
    p.bar   = (unsigned int*)alloc(4 * 64 * 4);
    p.h1x0  = (unsigned int*)alloc((size_t)N_ * 256 * 4);
    p.h1x1  = (unsigned int*)alloc((size_t)N_ * 256 * 4);
    p.h2x0  = (unsigned int*)alloc((size_t)N_ * 256 * 4);
    p.h2x1  = (unsigned int*)alloc((size_t)N_ * 256 * 4);
    p.h3xF  = (float*)alloc((size_t)N_ * 128 * 4);
    p.mqb   = (float*)alloc((size_t)N_ * 4 * 4);
    p.sqb   = (float*)alloc((size_t)N_ * 4 * 4);
    p.ctxqb = (float*)alloc((size_t)N_ * 4 * 128 * 4);
    size_t zbytes = (size_t)(w - zstart);

    hipMemsetAsync(zstart, 0, zbytes, stream);
    hipMemsetAsync((char*)d_out + (size_t)N_ * L_ * V_ * 4, 0,
                   (size_t)N_ * L_ * T_ * 4, stream);

    setup_weights<<<dim3(256), dim3(256), 0, stream>>>(p);
    setup_embproj<<<dim3(280), dim3(256), 0, stream>>>(p);
    setup_kv<<<dim3(2048), dim3(256), 0, stream>>>(p);

    // cooperative launch guarantees co-residency of all 256 WGs (required by barrier)
    void* args[] = { (void*)&p };
    hipLaunchCooperativeKernel((void*)decoder_main, dim3(256), dim3(512), args, 0, stream);
}

// Round 6
// 11099.438 us; speedup vs baseline: 1.1798x; 1.1798x over previous
//
#include <hip/hip_runtime.h>
#include <cstdint>
#include <cstddef>

#define T_ 2048
#define N_ 64
#define L_ 300
#define V_ 35
#define E_ 256
#define H_ 512
#define KS_ 128

typedef __attribute__((ext_vector_type(8))) short short8;
typedef __attribute__((ext_vector_type(4))) float float4v;

struct Params {
    // inputs (setup_inputs order)
    const float *key, *values;
    const int *x_lens, *text;
    const float *emb_W;
    const float *W_ih1, *W_hh1, *b_ih1, *b_hh1;
    const float *W_ih2, *W_hh2, *b_ih2, *b_hh2;
    const float *W_ih3, *W_hh3, *b_ih3, *b_hh3;
    const float *b_out;
    // workspace
    unsigned short *W1P, *W2P, *W3P;   // MFMA-fragment-packed bf16 weights
    float *embproj;                    // [V][2048] = emb_W@W_ih1[:,:256]^T + b_ih1 + b_hh1
    float *b2, *b3;
    unsigned short *keyP;              // packed A-frag layout [n][t16][kq][lane][8]
    unsigned short *valP;              // row-major [n][t][128] bf16
    unsigned int *bar;                 // [4 domains][64] flag array
    unsigned int *h1x0, *h1x1, *h2x0, *h2x1;  // [64][256] uint (bf16 pairs)
    float *h3xF;                       // [64][128] f32 h3 exchange
    float *mqb, *sqb;                  // [64*4] per-quarter max / sum
    float *ctxqb;                      // [64][4][128] per-quarter ctx partials
    float *out;
};

__device__ __forceinline__ float b2f(unsigned short u) {
    unsigned int i = ((unsigned int)u) << 16;
    float f; __builtin_memcpy(&f, &i, 4); return f;
}
__device__ __forceinline__ unsigned short f2b(float f) {
    unsigned int i; __builtin_memcpy(&i, &f, 4);
    i += 0x7FFFu + ((i >> 16) & 1u);
    return (unsigned short)(i >> 16);
}
__device__ __forceinline__ unsigned int packf2(float a, float b) {
    return (unsigned int)f2b(a) | ((unsigned int)f2b(b) << 16);
}
__device__ __forceinline__ float sigm(float x) { return 1.0f / (1.0f + __expf(-x)); }
__device__ __forceinline__ float tanh_(float x) {
    float e = __expf(2.0f * x);
    return 1.0f - 2.0f / (e + 1.0f);
}
__device__ __forceinline__ float wredsum(float v) {
#pragma unroll
    for (int o = 32; o > 0; o >>= 1) v += __shfl_down(v, o);
    return v;
}

// agent-scope coherent exchange primitives
__device__ __forceinline__ unsigned int cohLd(const unsigned int* p) {
    return __hip_atomic_load(p, __ATOMIC_RELAXED, __HIP_MEMORY_SCOPE_AGENT);
}
__device__ __forceinline__ void cohSt(unsigned int* p, unsigned int v) {
    __hip_atomic_store(p, v, __ATOMIC_RELAXED, __HIP_MEMORY_SCOPE_AGENT);
}
__device__ __forceinline__ float cohLdF(const float* p) {
    unsigned int u = __hip_atomic_load((const unsigned int*)p, __ATOMIC_RELAXED, __HIP_MEMORY_SCOPE_AGENT);
    float f; __builtin_memcpy(&f, &u, 4); return f;
}
__device__ __forceinline__ void cohStF(float* p, float v) {
    unsigned int u; __builtin_memcpy(&u, &v, 4);
    __hip_atomic_store((unsigned int*)p, u, __ATOMIC_RELAXED, __HIP_MEMORY_SCOPE_AGENT);
}

// Split flag-array barrier over a 64-WG domain.
// arrive: drain own publishes (vmcnt only) + set own flag (tid 0).
// wait:   EVERY wave polls all 64 flags (lane i polls flag i); a wave exits when
//         its exec mask empties (all 64 >= ep). No trailing __syncthreads needed:
//         prior-phase LDS use was quiesced by arrive's __syncthreads.
__device__ __forceinline__ void gbar_arrive(unsigned int* flags, int slot,
                                            unsigned int ep, int tid)
{
    asm volatile("s_waitcnt vmcnt(0)" ::: "memory");
    __syncthreads();
    if (tid == 0)
        __hip_atomic_store(flags + slot, ep, __ATOMIC_RELAXED, __HIP_MEMORY_SCOPE_AGENT);
}
__device__ __forceinline__ void gbar_wait(unsigned int* flags, unsigned int ep, int lane)
{
    while (__hip_atomic_load(flags + lane, __ATOMIC_RELAXED, __HIP_MEMORY_SCOPE_AGENT) < ep)
        __builtin_amdgcn_s_sleep(1);
}

struct __align__(16) ShAB {
    unsigned short xs[16][1032];     // staged A rows (K<=1024, +8 pad)
    float gld[2][4][16][16];         // [ntile][ksplit][col][m] partials
};
struct __align__(16) ShC {
    unsigned int xk3u[320];          // [h2(512)||h3prev(128)] bf16 pairs
    float g3L[4][32];                // gates for this WG's 32-hu slice
};
struct __align__(16) ShD {
    float attl[512];
    float ctxp[32][129];
    float red[128];
    float lsum[V_][8];
};
union __align__(16) ShU { ShAB ab; ShC c; ShD d; };

// Batched 16(m) x 32(cols) GEMM step; 8 waves = 2 ntiles x 4 k-splits.
// Weights come from LDS (W1L/W2L) -> ds_read_b128, zero L2 traffic.
template <int NKT>
__device__ __forceinline__ void gemm_ab(const unsigned short* xs,
                                        const unsigned short* wb,
                                        float (*gld)[4][16][16], int tid)
{
    const int lane = tid & 63, wv = tid >> 6;
    const int nt = wv & 1, ks = wv >> 1;
    constexpr int KTW = NKT / 4;
    float4v acc = {0.f, 0.f, 0.f, 0.f};
    const unsigned short* ar = xs + (lane & 15) * 1032 + ks * KTW * 32 + (lane >> 4) * 8;
    const unsigned short* wp = wb + ((size_t)(nt * NKT + ks * KTW)) * 512 + lane * 8;
#pragma unroll
    for (int k = 0; k < KTW; k++)
        acc = __builtin_amdgcn_mfma_f32_16x16x32_bf16(
            *(const short8*)(ar + k * 32), *(const short8*)(wp + (size_t)k * 512), acc, 0, 0, 0);
    const int q8 = lane >> 4, l15 = lane & 15;
#pragma unroll
    for (int r = 0; r < 4; r++) gld[nt][ks][l15][q8 * 4 + r] = acc[r];
}

__global__ __launch_bounds__(512) void decoder_main(Params p)
{
    __shared__ __align__(16) unsigned short W1L[20480];   // 40 KB cp-slice of W1P
    __shared__ __align__(16) unsigned short W2L[32768];   // 64 KB cp-slice of W2P
    __shared__ float c1L[128], c2L[128], c3L[32], h3sL[128];
    __shared__ float ctxf16[16][128];
    __shared__ float fL[16][4];
    __shared__ unsigned short h3bL[128];
    __shared__ ShU su;
    const int tid = threadIdx.x, wg = blockIdx.x;   // 256 WGs x 512
    const int lane = tid & 63, wv = tid >> 6;
    // XCD-aware role remap: xid = wg&7 (assumed XCD), jid = wg>>3.
    // cp = (xid<<3)|(jid&7): each XCD's 32 WGs share only 8 col-slices and ONE q
    // -> W3P q-slice (164KB) + embproj stay L2-resident per XCD.
    const int xid = wg & 7, jid = wg >> 3;
    const int cp = (xid << 3) | (jid & 7);          // col-slice 0..63
    const int mt = (jid >> 3) & 3;                  // barrier domain
    const int ownr = cp & 15, q = cp >> 4;          // attention role
    const int n = mt * 16 + ownr;
    const int len = p.x_lens[n];
    // interleaved t16-tile assignment: WG q owns tiles {4k+q}, k in [0,32)
    const int kmax = (len > 16 * q) ? min(32, (len - 16 * q + 63) >> 6) : 0;
    const int RQ = kmax << 4;                       // local rows (attl index bound)
    const int tglT = 64 * (tid >> 4) + 16 * q + (tid & 15);  // tid -> global t
    float* const attnout = p.out + (size_t)N_ * L_ * V_ + (size_t)n * L_ * T_;
    unsigned int* const flags = p.bar + mt * 64;    // mt-local barrier domain
    unsigned int ep = 0;

    // one-time: weight slices -> LDS
    {
        const short8* W1g = (const short8*)(p.W1P + (size_t)cp * (2 * 20 * 512));
        const short8* W2g = (const short8*)(p.W2P + (size_t)cp * (2 * 32 * 512));
#pragma unroll
        for (int i = 0; i < 5; i++) ((short8*)W1L)[tid + i * 512] = W1g[tid + i * 512];
#pragma unroll
        for (int i = 0; i < 8; i++) ((short8*)W2L)[tid + i * 512] = W2g[tid + i * 512];
    }
    if (tid < 128) { c1L[tid] = 0.f; c2L[tid] = 0.f; h3sL[tid] = 0.f; }
    if (tid < 32) c3L[tid] = 0.f;
    __syncthreads();

    const unsigned short* W3b = p.W3P + (size_t)(q * 8) * (20 * 512);

    unsigned int prefH1[10];      // phase-A staging prefetch (h1prev part)
#pragma unroll
    for (int i = 0; i < 10; i++) prefH1[i] = 0u;   // h1_0 = 0

    // flash-combine for step lp: att write (own tiles), ctx for own 16 rows, logits (q0)
    auto combine = [&](int lp) {
        const int nr = tid >> 5, e0i = (tid & 31) * 4;
        float cq[4][4];
#pragma unroll
        for (int qq = 0; qq < 4; qq++) {
            const float* b = p.ctxqb + ((size_t)(mt * 16 + nr) * 4 + qq) * 128 + e0i;
#pragma unroll
            for (int j = 0; j < 4; j++) cq[qq][j] = cohLdF(b + j);
        }
        if (tid < 64)       su.d.red[tid] = cohLdF(p.mqb + mt * 64 + tid);
        else if (tid < 128) su.d.red[tid] = cohLdF(p.sqb + mt * 64 + (tid - 64));
        __syncthreads();
        if (tid < 16) {
            float m0 = su.d.red[tid * 4], m1 = su.d.red[tid * 4 + 1],
                  m2 = su.d.red[tid * 4 + 2], m3 = su.d.red[tid * 4 + 3];
            float M = fmaxf(fmaxf(m0, m1), fmaxf(m2, m3));
            float e0 = __expf(m0 - M), e1 = __expf(m1 - M),
                  e2 = __expf(m2 - M), e3 = __expf(m3 - M);
            float S = su.d.red[64 + tid * 4] * e0 + su.d.red[64 + tid * 4 + 1] * e1
                    + su.d.red[64 + tid * 4 + 2] * e2 + su.d.red[64 + tid * 4 + 3] * e3;
            float rS = 1.0f / S;
            fL[tid][0] = e0 * rS; fL[tid][1] = e1 * rS;
            fL[tid][2] = e2 * rS; fL[tid][3] = e3 * rS;
        }
        __syncthreads();
        {
            float fq = fL[ownr][q];
            if (tglT < len)
                __builtin_nontemporal_store(su.d.attl[tid] * fq,
                                            attnout + (size_t)lp * T_ + tglT);
        }
        {
            float s0 = 0.f, s1 = 0.f, s2 = 0.f, s3 = 0.f;
#pragma unroll
            for (int qq = 0; qq < 4; qq++) {
                float f = fL[nr][qq];
                s0 += cq[qq][0] * f; s1 += cq[qq][1] * f;
                s2 += cq[qq][2] * f; s3 += cq[qq][3] * f;
            }
            ctxf16[nr][e0i] = s0; ctxf16[nr][e0i + 1] = s1;
            ctxf16[nr][e0i + 2] = s2; ctxf16[nr][e0i + 3] = s3;
        }
        __syncthreads();
        if (q == 0) {   // logits for own n (q is WG-uniform; inner barriers safe)
            if (tid < V_ * 8) {
                const int v = tid >> 3, oc = tid & 7;
                const float* er = p.emb_W + (size_t)v * E_ + oc * 32;
                const float* src = (oc < 4) ? (h3sL + oc * 32) : (&ctxf16[ownr][0] + oc * 32 - 128);
                float s = 0.f;
#pragma unroll
                for (int j2 = 0; j2 < 32; j2++) s += src[j2] * er[j2];
                su.d.lsum[v][oc] = s;
            }
            __syncthreads();
            if (tid < V_) {
                float s = p.b_out[tid];
#pragma unroll
                for (int j2 = 0; j2 < 8; j2++) s += su.d.lsum[tid][j2];
                p.out[((size_t)n * L_ + lp) * V_ + tid] = s;
            }
        }
    };

    for (int l = 0; l < L_; ++l) {
        const unsigned int* h2prev = (l & 1) ? p.h2x1 : p.h2x0;
        unsigned int* h1cur        = (l & 1) ? p.h1x0 : p.h1x1;
        unsigned int* h2cur        = (l & 1) ? p.h2x0 : p.h2x1;

        // ===== Phase A: combine(l-1) + LSTM1 (K = [ctx||h1prev], emb in embproj) =====
        gbar_wait(flags, ep, lane);          // D1(l-1) done (trivial at l==0)
        float ebv[4] = {0.f, 0.f, 0.f, 0.f};
        if (tid < 128) {
            const int m2e = mt * 16 + (tid & 15);
            const float* eb = p.embproj + (size_t)p.text[m2e * L_ + l] * 2048
                            + cp * 8 + (tid >> 4);
#pragma unroll
            for (int g = 0; g < 4; g++) ebv[g] = eb[g * 512];
        }
        if (l > 0) {
            combine(l - 1);
        } else {
            float* cf = &ctxf16[0][0];
            cf[tid * 4] = 0.f; cf[tid * 4 + 1] = 0.f;
            cf[tid * 4 + 2] = 0.f; cf[tid * 4 + 3] = 0.f;
        }
        __syncthreads();
        {
            unsigned int* xsu = (unsigned int*)&su.ab.xs[0][0];
#pragma unroll
            for (int i = 0; i < 10; i++) {
                int idx = tid + i * 512;
                int r = idx / 320, c = idx - r * 320;
                unsigned int u = (c < 64)
                    ? packf2(ctxf16[r][2 * c], ctxf16[r][2 * c + 1])
                    : prefH1[i];
                xsu[r * 516 + c] = u;
            }
        }
        __syncthreads();
        gemm_ab<20>(&su.ab.xs[0][0], W1L, su.ab.gld, tid);
        __syncthreads();
        if (tid < 128) {
            const int mm = tid & 15, jj = tid >> 4;
            const int m2 = mt * 16 + mm;
            float gv[4];
#pragma unroll
            for (int g = 0; g < 4; g++) {
                int ntq = g >> 1, lq = (g & 1) * 8 + jj;
                float s = 0.f;
#pragma unroll
                for (int k2 = 0; k2 < 4; k2++) s += su.ab.gld[ntq][k2][lq][mm];
                gv[g] = s + ebv[g];
            }
            float c = sigm(gv[1]) * c1L[tid] + sigm(gv[0]) * tanh_(gv[2]);
            c1L[tid] = c;
            unsigned int hb = (unsigned int)f2b(sigm(gv[3]) * tanh_(c));
            unsigned int ob = (unsigned int)__shfl_xor((int)hb, 16);
            if (!(jj & 1)) cohSt(h1cur + m2 * 256 + cp * 4 + (jj >> 1), hb | (ob << 16));
        }
        ++ep; gbar_arrive(flags, cp, ep, tid);

        // prefetch h2prev (stable since last step's B) while barrier propagates
        unsigned int prefH2[16];
        if (tid >= 256) {
#pragma unroll
            for (int i = 0; i < 16; i++)
                prefH2[i] = cohLd(h2prev + (mt * 16 + i) * 256 + (tid - 256));
        }
        gbar_wait(flags, ep, lane);

        // ===== Phase B: LSTM2, K = [h1(512)||h2prev(512)] =====
        {
            unsigned int* xsu = (unsigned int*)&su.ab.xs[0][0];
#pragma unroll
            for (int i = 0; i < 16; i++) {
                unsigned int u = (tid < 256) ? cohLd(h1cur + (mt * 16 + i) * 256 + tid)
                                             : prefH2[i];
                xsu[i * 516 + tid] = u;
            }
            __syncthreads();
            gemm_ab<32>(&su.ab.xs[0][0], W2L, su.ab.gld, tid);
            __syncthreads();
            if (tid < 128) {
                const int mm = tid & 15, jj = tid >> 4;
                const int m2 = mt * 16 + mm;
                float gv[4];
#pragma unroll
                for (int g = 0; g < 4; g++) {
                    int ntq = g >> 1, lq = (g & 1) * 8 + jj;
                    float s = 0.f;
#pragma unroll
                    for (int k2 = 0; k2 < 4; k2++) s += su.ab.gld[ntq][k2][lq][mm];
                    gv[g] = s + p.b2[g * 512 + cp * 8 + jj];
                }
                float c = sigm(gv[1]) * c2L[tid] + sigm(gv[0]) * tanh_(gv[2]);
                c2L[tid] = c;
                unsigned int hb = (unsigned int)f2b(sigm(gv[3]) * tanh_(c));
                unsigned int ob = (unsigned int)__shfl_xor((int)hb, 16);
                if (!(jj & 1)) cohSt(h2cur + m2 * 256 + cp * 4 + (jj >> 1), hb | (ob << 16));
            }
        }
        ++ep; gbar_arrive(flags, cp, ep, tid);
        gbar_wait(flags, ep, lane);

        // ===== Phase C: LSTM3 gates (col-sliced MFMA, W3 L2-resident) + h3 exchange =====
        {
            if (tid < 256) su.c.xk3u[tid] = cohLd(h2cur + n * 256 + tid);
            if (tid >= 256 && tid < 320) {
                int i2 = tid - 256;
                su.c.xk3u[256 + i2] = packf2(h3sL[2 * i2], h3sL[2 * i2 + 1]);
            }
            __syncthreads();
            const unsigned short* xb = (const unsigned short*)su.c.xk3u;
            const int q8 = lane >> 4;
            float4v acc = {0.f, 0.f, 0.f, 0.f};
            const unsigned short* ap = W3b + (size_t)wv * (20 * 512) + lane * 8;
#pragma unroll
            for (int kt = 0; kt < 20; kt++)
                acc = __builtin_amdgcn_mfma_f32_16x16x32_bf16(
                    *(const short8*)(ap + (size_t)kt * 512),
                    *(const short8*)(xb + kt * 32 + q8 * 8), acc, 0, 0, 0);
            if ((lane & 15) == 0) {
                const int g = wv >> 1, hl = (wv & 1) * 16 + q8 * 4;
                const float4v bb = *(const float4v*)(p.b3 + g * 128 + q * 32 + hl);
#pragma unroll
                for (int r = 0; r < 4; r++) su.c.g3L[g][hl + r] = acc[r] + bb[r];
            }
            __syncthreads();
            if (tid < 32) {
                float gi = sigm(su.c.g3L[0][tid]);
                float gf = sigm(su.c.g3L[1][tid]);
                float gg = tanh_(su.c.g3L[2][tid]);
                float go = sigm(su.c.g3L[3][tid]);
                float c = gf * c3L[tid] + gi * gg;
                c3L[tid] = c;
                cohStF(p.h3xF + n * 128 + q * 32 + tid, go * tanh_(c));
            }
        }
        ++ep; gbar_arrive(flags, cp, ep, tid);

        // prefetch key fragments (input-constant, interleaved tiles, NT) during barrier
        short8 kf[4][4];
        {
            const unsigned short* kpb = p.keyP + (size_t)n * (128 * 2048);
#pragma unroll
            for (int i = 0; i < 4; i++) {
                int g = 4 * (wv * 4 + i) + q;
                if (g * 16 < len) {
                    const unsigned short* ab2 = kpb + (size_t)g * 2048 + lane * 8;
                    kf[i][0] = __builtin_nontemporal_load((const short8*)(ab2));
                    kf[i][1] = __builtin_nontemporal_load((const short8*)(ab2 + 512));
                    kf[i][2] = __builtin_nontemporal_load((const short8*)(ab2 + 1024));
                    kf[i][3] = __builtin_nontemporal_load((const short8*)(ab2 + 1536));
                }
            }
        }
        gbar_wait(flags, ep, lane);

        // ===== Phase D1: energies (MFMA) + local softmax + ctx partial =====
        {
            if (tid < 128) {
                float h = cohLdF(p.h3xF + n * 128 + tid);
                h3sL[tid] = h;
                h3bL[tid] = f2b(h);
            }
            __syncthreads();
            const int q8 = lane >> 4, l15 = lane & 15;
            short8 bfr[4];
#pragma unroll
            for (int kq = 0; kq < 4; kq++)
                bfr[kq] = *(const short8*)(h3bL + kq * 32 + q8 * 8);
            float mloc = -1e30f;
#pragma unroll
            for (int i = 0; i < 4; i++) {
                int kloc = wv * 4 + i;
                int g = 4 * kloc + q;
                if (g * 16 < len) {
                    float4v acc = {0.f, 0.f, 0.f, 0.f};
                    acc = __builtin_amdgcn_mfma_f32_16x16x32_bf16(kf[i][0], bfr[0], acc, 0, 0, 0);
                    acc = __builtin_amdgcn_mfma_f32_16x16x32_bf16(kf[i][1], bfr[1], acc, 0, 0, 0);
                    acc = __builtin_amdgcn_mfma_f32_16x16x32_bf16(kf[i][2], bfr[2], acc, 0, 0, 0);
                    acc = __builtin_amdgcn_mfma_f32_16x16x32_bf16(kf[i][3], bfr[3], acc, 0, 0, 0);
                    int rbase = g * 16 + q8 * 4;
#pragma unroll
                    for (int r = 0; r < 4; r++) {
                        float e = (rbase + r < len) ? acc[r] : -1e30f;
                        acc[r] = e;
                        mloc = fmaxf(mloc, e);
                    }
                    if (l15 == 0) *(float4v*)(su.d.attl + kloc * 16 + q8 * 4) = acc;
                } else if (l15 == 0) {
                    float4v z = {0.f, 0.f, 0.f, 0.f};
                    *(float4v*)(su.d.attl + kloc * 16 + q8 * 4) = z;
                }
            }
            mloc = fmaxf(mloc, __shfl_xor(mloc, 16));
            mloc = fmaxf(mloc, __shfl_xor(mloc, 32));
            if (lane == 0) su.d.red[96 + wv] = mloc;
            __syncthreads();
            float M2 = su.d.red[96];
#pragma unroll
            for (int i2 = 1; i2 < 8; i2++) M2 = fmaxf(M2, su.d.red[96 + i2]);
            float pv = (tglT < len) ? __expf(su.d.attl[tid] - M2) : 0.f;
            su.d.attl[tid] = pv;
            float ps = wredsum(pv);
            if (lane == 0) su.d.red[104 + wv] = ps;
            __syncthreads();
            if (tid == 0) {
                float s = 0.f;
                for (int i2 = 0; i2 < 8; i2++) s += su.d.red[104 + i2];
                cohStF(p.mqb + n * 4 + q, M2);
                cohStF(p.sqb + n * 4 + q, s);
            }
            // ctx partial (unnormalized), interleaved tiles, 4-deep NT val stream
            {
                const int tg = tid >> 4, e8 = tid & 15;
                float a8[8] = {0, 0, 0, 0, 0, 0, 0, 0};
                const unsigned short* vb = p.valP
                    + ((size_t)n * 2048 + 64 * (tg >> 4) + (tg & 15) + 16 * q) * 128 + e8 * 8;
                const int smax = (RQ > tg) ? ((RQ - tg + 31) >> 5) : 0;
                int s = 0;
                for (; s + 3 < smax; s += 4) {
                    const unsigned short* vp = vb + (size_t)s * 16384;
                    short8 v0 = __builtin_nontemporal_load((const short8*)(vp));
                    short8 v1 = __builtin_nontemporal_load((const short8*)(vp + 16384));
                    short8 v2 = __builtin_nontemporal_load((const short8*)(vp + 32768));
                    short8 v3 = __builtin_nontemporal_load((const short8*)(vp + 49152));
                    float w0 = su.d.attl[tg + 32 * s],       w1 = su.d.attl[tg + 32 * (s + 1)];
                    float w2 = su.d.attl[tg + 32 * (s + 2)], w3 = su.d.attl[tg + 32 * (s + 3)];
#pragma unroll
                    for (int j = 0; j < 8; j++)
                        a8[j] += w0 * b2f((unsigned short)v0[j]) + w1 * b2f((unsigned short)v1[j])
                               + w2 * b2f((unsigned short)v2[j]) + w3 * b2f((unsigned short)v3[j]);
                }
                for (; s < smax; s++) {
                    float w = su.d.attl[tg + 32 * s];
                    short8 v8 = __builtin_nontemporal_load((const short8*)(vb + (size_t)s * 16384));
#pragma unroll
                    for (int j = 0; j < 8; j++) a8[j] += w * b2f((unsigned short)v8[j]);
                }
#pragma unroll
                for (int j = 0; j < 8; j++) su.d.ctxp[tg][e8 * 8 + j] = a8[j];
            }
            __syncthreads();
            if (tid < 128) {
                float s = 0.f;
#pragma unroll 8
                for (int g2 = 0; g2 < 32; g2++) s += su.d.ctxp[g2][tid];
                cohStF(p.ctxqb + ((size_t)n * 4 + q) * 128 + tid, s);
            }
        }
        ++ep; gbar_arrive(flags, cp, ep, tid);

        // prefetch next step's h1prev (= h1cur published in this step's A; stable)
        if (l + 1 < L_) {
#pragma unroll
            for (int i = 0; i < 10; i++) {
                int idx = tid + i * 512;
                int r = idx / 320, c = idx - r * 320;
                if (c >= 64)
                    prefH1[i] = cohLd(h1cur + (mt * 16 + r) * 256 + (c - 64));
            }
        }
    }
    // final step's att + logits
    gbar_wait(flags, ep, lane);
    combine(L_ - 1);
}

// ---------------- setup kernels ----------------
__global__ void setup_weights(Params p)
{
    size_t stride = (size_t)gridDim.x * blockDim.x;
    size_t i0 = (size_t)blockIdx.x * blockDim.x + threadIdx.x;
    // W1P [cp][nt][kt20][lane][8]; K = [ctx(128)->W_ih1 cols 256.. || h1(512)->W_hh1]
    for (size_t i = i0; i < (size_t)1310720; i += stride) {
        int e = (int)(i & 7), ln = (int)((i >> 3) & 63), blk = (int)(i >> 9);
        int kt = blk % 20, nt = (blk / 20) & 1, cpp = blk / 40;
        int l15 = ln & 15, q8 = ln >> 4;
        int col = (2 * nt + (l15 >> 3)) * 512 + cpp * 8 + (l15 & 7);
        int k = kt * 32 + q8 * 8 + e;
        float v = (k < 128) ? p.W_ih1[(size_t)col * 384 + 256 + k]
                            : p.W_hh1[(size_t)col * 512 + (k - 128)];
        p.W1P[i] = f2b(v);
    }
    // W2P [cp][nt][kt32][lane][8]; K = [h1 || h2prev]
    for (size_t i = i0; i < (size_t)2097152; i += stride) {
        int e = (int)(i & 7), ln = (int)((i >> 3) & 63), blk = (int)(i >> 9);
        int kt = blk & 31, nt = (blk >> 5) & 1, cpp = blk >> 6;
        int l15 = ln & 15, q8 = ln >> 4;
        int col = (2 * nt + (l15 >> 3)) * 512 + cpp * 8 + (l15 & 7);
        int k = kt * 32 + q8 * 8 + e;
        float v = (k < 512) ? p.W_ih2[(size_t)col * 512 + k]
                            : p.W_hh2[(size_t)col * 512 + (k - 512)];
        p.W2P[i] = f2b(v);
    }
    // W3P [q][tile8][kt20][lane][8]; rows = gate cols; K = [h2(512) || h3prev(128)]
    for (size_t i = i0; i < (size_t)327680; i += stride) {
        int e = (int)(i & 7), ln = (int)((i >> 3) & 63), blk = (int)(i >> 9);
        int kt = blk % 20, tile = (blk / 20) & 7, qq = blk / 160;
        int l15 = ln & 15, q8 = ln >> 4;
        int col = (tile >> 1) * 128 + qq * 32 + (tile & 1) * 16 + l15;
        int k = kt * 32 + q8 * 8 + e;
        float v = (k < 512) ? p.W_ih3[(size_t)col * 512 + k]
                            : p.W_hh3[(size_t)col * 128 + (k - 512)];
        p.W3P[i] = f2b(v);
    }
    for (size_t i = i0; i < 2048; i += stride) p.b2[i] = p.b_ih2[i] + p.b_hh2[i];
    for (size_t i = i0; i < 512; i += stride) p.b3[i] = p.b_ih3[i] + p.b_hh3[i];
}

// embproj[c][j] = emb_W[c] . W_ih1[j][:256] + b_ih1[j] + b_hh1[j]
__global__ void setup_embproj(Params p)
{
    int idx = blockIdx.x * blockDim.x + threadIdx.x;
    if (idx >= V_ * 2048) return;
    int c = idx >> 11, j = idx & 2047;
    float s = p.b_ih1[j] + p.b_hh1[j];
    const float* er = p.emb_W + (size_t)c * E_;
    const float* wr = p.W_ih1 + (size_t)j * 384;
    for (int k = 0; k < 256; k++) s += er[k] * wr[k];
    p.embproj[idx] = s;
}

__global__ void setup_kv(Params p)
{
    size_t stride = (size_t)gridDim.x * blockDim.x;
    const size_t total = (size_t)T_ * N_ * KS_;
    for (size_t idx = (size_t)blockIdx.x * blockDim.x + threadIdx.x; idx < total; idx += stride) {
        int t = (int)(idx >> 13);
        int rem = (int)(idx & 8191);
        int n = rem >> 7, k = rem & 127;
        p.valP[((size_t)n * 2048 + t) * 128 + k] = f2b(p.values[idx]);
        size_t dst = (((size_t)n * 128 + (t >> 4)) * 4 + (k >> 5)) * 512
                   + ((((k >> 3) & 3) * 16 + (t & 15)) * 8) + (k & 7);
        p.keyP[dst] = f2b(p.key[idx]);
    }
}

// ---------------- host ----------------
extern "C" void kernel_launch(void* const* d_in, const int* in_sizes, int n_in,
                              void* d_out, int out_size, void* d_ws, size_t ws_size,
                              hipStream_t stream)
{
    (void)in_sizes; (void)n_in; (void)out_size; (void)ws_size;
    Params p;
    p.key    = (const float*)d_in[0];
    p.values = (const float*)d_in[1];
    p.x_lens = (const int*)d_in[2];
    p.text   = (const int*)d_in[3];
    p.emb_W  = (const float*)d_in[4];
    p.W_ih1  = (const float*)d_in[5];
    p.W_hh1  = (const float*)d_in[6];
    p.b_ih1  = (const float*)d_in[7];
    p.b_hh1  = (const float*)d_in[8];
    p.W_ih2  = (const float*)d_in[9];
    p.W_hh2  = (const float*)d_in[10];
    p.b_ih2  = (const float*)d_in[11];
    p.b_hh2  = (const float*)d_in[12];
    p.W_ih3  = (const float*)d_in[13];
    p.W_hh3  = (const float*)d_in[14];
    p.b_ih3  = (const float*)d_in[15];
    p.b_hh3  = (const float*)d_in[16];
    p.b_out  = (const float*)d_in[17];
    p.out    = (float*)d_out;

    char* w = (char*)d_ws;
    auto alloc = [&](size_t bytes) -> char* {
        char* r = w;
        w += (bytes + 255) & ~(size_t)255;
        return r;
    };
    p.W1P     = (unsigned short*)alloc((size_t)1310720 * 2);
    p.W2P     = (unsigned short*)alloc((size_t)2097152 * 2);
    p.W3P     = (unsigned short*)alloc((size_t)327680 * 2);
    p.embproj = (float*)alloc((size_t)V_ * 2048 * 4);
    p.b2      = (float*)alloc(2048 * 4);
    p.b3      = (float*)alloc(512 * 4);
    p.keyP    = (unsigned short*)alloc((size_t)16777216 * 2);
    p.valP    = (unsigned short*)alloc((size_t)16777216 * 2);
    char* zstart = w;
    p.bar   = (unsigned int*)alloc(4 * 64 * 4);
    p.h1x0  = (unsigned int*)alloc((size_t)N_ * 256 * 4);
    p.h1x1  = (unsigned int*)alloc((size_t)N_ * 256 * 4);
    p.h2x0  = (unsigned int*)alloc((size_t)N_ * 256 * 4);
    p.h2x1  = (unsigned int*)alloc((size_t)N_ * 256 * 4);
    p.h3xF  = (float*)alloc((size_t)N_ * 128 * 4);
    p.mqb   = (float*)alloc((size_t)N_ * 4 * 4);
    p.sqb   = (float*)alloc((size_t)N_ * 4 * 4);
    p.ctxqb = (float*)alloc((size_t)N_ * 4 * 128 * 4);
    size_t zbytes = (size_t)(w - zstart);

    hipMemsetAsync(zstart, 0, zbytes, stream);
    hipMemsetAsync((char*)d_out + (size_t)N_ * L_ * V_ * 4, 0,
                   (size_t)N_ * L_ * T_ * 4, stream);

    setup_weights<<<dim3(256), dim3(256), 0, stream>>>(p);
    setup_embproj<<<dim3(280), dim3(256), 0, stream>>>(p);
    setup_kv<<<dim3(2048), dim3(256), 0, stream>>>(p);

    // cooperative launch guarantees co-residency of all 256 WGs (required by barrier)
    void* args[] = { (void*)&p };
    hipLaunchCooperativeKernel((void*)decoder_main, dim3(256), dim3(512), args, 0, stream);
}